// Round 2
// baseline (87.570 us; speedup 1.0000x reference)
//
#include <hip/hip_runtime.h>
#include <hip/hip_bf16.h>

#define N 8192
#define DIMS 128
#define NSLICE 16
#define SLICE_COLS (N / NSLICE)     // 512
#define SUBTILES (SLICE_COLS / 16)  // 32 (even, required by 2x unroll)
#define ROWS_PER_BLOCK 128
#define STRIPS 2                    // 16-row strips per wave
#define NROWBLK (N / ROWS_PER_BLOCK)  // 64
#define NFIN 2048                   // finalize block count
#define MARGIN_F 0.2f
#define EPS_F 1e-6f
#define INF_F __builtin_huge_valf()

typedef __bf16 bf16x8 __attribute__((ext_vector_type(8)));
typedef float f32x4 __attribute__((ext_vector_type(4)));

// ws layout (bytes):
//   Xb   : ushort[N*DIMS]      @ 0          (2 MiB)   bf16 features
//   meta : float2[N]           @ 2097152    (64 KiB)  {sq, label bits}
//   part : float4[NSLICE*N]    @ 2162688    (2 MiB)   per-slice {bpv, bpi, bnv, bni}
//   bsum : float2[NFIN]        @ 4259840    (16 KiB)
#define XB_OFF   0
#define META_OFF 2097152
#define PART_OFF 2162688
#define BSUM_OFF 4259840

// ---------------- prep: fp32 -> bf16, row sq-norm, pack label -------------
__global__ __launch_bounds__(256) void prep_kernel(
    const float* __restrict__ feat, const int* __restrict__ lab,
    unsigned short* __restrict__ Xb, float2* __restrict__ meta) {
  int row = blockIdx.x * 4 + (threadIdx.x >> 6);
  int lane = threadIdx.x & 63;
  float2 x = *reinterpret_cast<const float2*>(feat + (size_t)row * DIMS + lane * 2);
  __hip_bfloat16 hx = __float2bfloat16(x.x);
  __hip_bfloat16 hy = __float2bfloat16(x.y);
  unsigned short ux, uy;
  __builtin_memcpy(&ux, &hx, 2);
  __builtin_memcpy(&uy, &hy, 2);
  unsigned int packed = (unsigned int)ux | ((unsigned int)uy << 16);
  *reinterpret_cast<unsigned int*>(Xb + (size_t)row * DIMS + lane * 2) = packed;
  float s = x.x * x.x + x.y * x.y;
#pragma unroll
  for (int m = 32; m >= 1; m >>= 1) s += __shfl_xor(s, m, 64);
  if (lane == 0) meta[row] = make_float2(s, __int_as_float(lab[row]));
}

// ---------------- mine: fused bf16 MFMA GEMM + batch-hard mining ----------
// grid = NROWBLK * NSLICE = 1024 blocks, 256 threads (4 waves), 4 blocks/CU.
// Each wave owns 32 anchor rows (2 strips of 16); scans SLICE_COLS columns.
__global__ __launch_bounds__(256, 4) void mine_kernel(
    const unsigned short* __restrict__ Xb, const float2* __restrict__ meta,
    const int* __restrict__ lab, float4* __restrict__ part) {
  int rb = blockIdx.x / NSLICE;
  int sl = blockIdx.x % NSLICE;
  int wave = threadIdx.x >> 6;
  int lane = threadIdx.x & 63;
  int lrow = lane & 15;   // A-row / B-col / C-col lane index
  int lk = lane >> 4;     // k-subgroup; also C-row group
  int rowbase = rb * ROWS_PER_BLOCK + wave * (STRIPS * 16);

  // A fragments: STRIPS x 4 k-groups, held in registers for the whole scan
  bf16x8 afrag[STRIPS][4];
#pragma unroll
  for (int s = 0; s < STRIPS; ++s) {
    const unsigned short* rp = Xb + (size_t)(rowbase + s * 16 + lrow) * DIMS;
#pragma unroll
    for (int g = 0; g < 4; ++g)
      afrag[s][g] = *reinterpret_cast<const bf16x8*>(rp + g * 32 + lk * 8);
  }
  // labels of the epilogue rows per strip (C rows = lk*4 + e)
  int4 labi[STRIPS];
#pragma unroll
  for (int s = 0; s < STRIPS; ++s)
    labi[s] = *reinterpret_cast<const int4*>(lab + rowbase + s * 16 + lk * 4);

  float bpv[STRIPS][4], bnv[STRIPS][4];
  int bpi[STRIPS][4], bni[STRIPS][4];
#pragma unroll
  for (int s = 0; s < STRIPS; ++s)
#pragma unroll
    for (int e = 0; e < 4; ++e) {
      bpv[s][e] = -INF_F; bnv[s][e] = INF_F; bpi[s][e] = 0; bni[s][e] = 0;
    }

  int j0 = sl * SLICE_COLS;

  auto loadB = [&](bf16x8* bb, float2& m, int tt) {
    int j = j0 + tt * 16 + lrow;
    m = meta[j];
    const unsigned short* cp = Xb + (size_t)j * DIMS;
#pragma unroll
    for (int g = 0; g < 4; ++g)
      bb[g] = *reinterpret_cast<const bf16x8*>(cp + g * 32 + lk * 8);
  };

  auto compute = [&](const bf16x8* bb, float2 m, int tt) {
    int jcur = j0 + tt * 16 + lrow;
    float sqj = m.x;
    int labj = __float_as_int(m.y);
#pragma unroll
    for (int s = 0; s < STRIPS; ++s) {
      f32x4 acc = {0.f, 0.f, 0.f, 0.f};
#pragma unroll
      for (int g = 0; g < 4; ++g)
        acc = __builtin_amdgcn_mfma_f32_16x16x32_bf16(afrag[s][g], bb[g], acc, 0, 0, 0);
      int labs[4] = {labi[s].x, labi[s].y, labi[s].z, labi[s].w};
#pragma unroll
      for (int e = 0; e < 4; ++e) {
        float key = fmaf(-2.0f, acc[e], sqj);
        bool pos = (labj == labs[e]);
        bool gp = pos && (key > bpv[s][e]);
        bool gn = (!pos) && (key < bnv[s][e]);
        bpv[s][e] = gp ? key : bpv[s][e];
        bpi[s][e] = gp ? jcur : bpi[s][e];
        bnv[s][e] = gn ? key : bnv[s][e];
        bni[s][e] = gn ? jcur : bni[s][e];
      }
    }
  };

  // 2x-unrolled software pipeline with A/B role swap (no register copies)
  bf16x8 bufA[4], bufB[4];
  float2 mA, mB;
  loadB(bufA, mA, 0);
  for (int t = 0; t < SUBTILES; t += 2) {
    loadB(bufB, mB, t + 1);
    compute(bufA, mA, t);
    int tn = (t + 2 < SUBTILES) ? (t + 2) : (t + 1);  // harmless clamp reload
    loadB(bufA, mA, tn);
    compute(bufB, mB, t + 1);
  }

  // merge across the 16 lanes that share each C-row (lane bits 0-3)
#pragma unroll
  for (int s = 0; s < STRIPS; ++s) {
#pragma unroll
    for (int e = 0; e < 4; ++e) {
      float pv = bpv[s][e]; int pi = bpi[s][e];
      float nv = bnv[s][e]; int ni = bni[s][e];
#pragma unroll
      for (int m = 1; m < 16; m <<= 1) {
        float opv = __shfl_xor(pv, m, 64); int opi = __shfl_xor(pi, m, 64);
        float onv = __shfl_xor(nv, m, 64); int oni = __shfl_xor(ni, m, 64);
        bool tp = (opv > pv) || (opv == pv && opi < pi);
        pv = tp ? opv : pv; pi = tp ? opi : pi;
        bool tn = (onv < nv) || (onv == nv && oni < ni);
        nv = tn ? onv : nv; ni = tn ? oni : ni;
      }
      if (lrow == 0) {
        int row = rowbase + s * 16 + lk * 4 + e;
        part[(size_t)sl * N + row] =
            make_float4(pv, __int_as_float(pi), nv, __int_as_float(ni));
      }
    }
  }
}

// ---------------- finalize: wave-per-anchor merge + exact fp32 hinge ------
// grid = N/4 = 2048 blocks x 256 threads; each wave owns one anchor row.
__global__ __launch_bounds__(256) void finalize_kernel(
    const float* __restrict__ feat, const float4* __restrict__ part,
    float2* __restrict__ bsum) {
  int wave = threadIdx.x >> 6, lane = threadIdx.x & 63;
  int i = blockIdx.x * 4 + wave;

  float pv = -INF_F, nv = INF_F;
  int pi = 0, ni = 0;
  if (lane < NSLICE) {
    float4 p = part[(size_t)lane * N + i];
    pv = p.x; pi = __float_as_int(p.y);
    nv = p.z; ni = __float_as_int(p.w);
  }
#pragma unroll
  for (int m = 1; m < 16; m <<= 1) {
    float opv = __shfl_xor(pv, m, 64); int opi = __shfl_xor(pi, m, 64);
    float onv = __shfl_xor(nv, m, 64); int oni = __shfl_xor(ni, m, 64);
    bool tp = (opv > pv) || (opv == pv && opi < pi);
    pv = tp ? opv : pv; pi = tp ? opi : pi;
    bool tn = (onv < nv) || (onv == nv && oni < ni);
    nv = tn ? onv : nv; ni = tn ? oni : ni;
  }
  pi = __shfl(pi, 0, 64);
  ni = __shfl(ni, 0, 64);
  float nvb = __shfl(nv, 0, 64);
  bool valid = (nvb < INF_F);

  float2 av = *reinterpret_cast<const float2*>(feat + (size_t)i * DIMS + lane * 2);
  float2 pw = *reinterpret_cast<const float2*>(feat + (size_t)pi * DIMS + lane * 2);
  float2 nw = *reinterpret_cast<const float2*>(feat + (size_t)ni * DIMS + lane * 2);
  float d0 = av.x - pw.x + EPS_F, d1 = av.y - pw.y + EPS_F;
  float sp = fmaf(d0, d0, d1 * d1);
  float e0 = av.x - nw.x + EPS_F, e1 = av.y - nw.y + EPS_F;
  float sn = fmaf(e0, e0, e1 * e1);
#pragma unroll
  for (int m = 32; m >= 1; m >>= 1) {
    sp += __shfl_xor(sp, m, 64);
    sn += __shfl_xor(sn, m, 64);
  }

  __shared__ float s_s[4], s_c[4];
  if (lane == 0) {
    float per = sqrtf(sp) - sqrtf(sn) + MARGIN_F;
    per = per > 0.f ? per : 0.f;
    per = valid ? per : 0.f;
    s_s[wave] = per;
    s_c[wave] = valid ? 1.f : 0.f;
  }
  __syncthreads();
  if (threadIdx.x == 0) {
    float ts = (s_s[0] + s_s[1]) + (s_s[2] + s_s[3]);
    float tc = (s_c[0] + s_c[1]) + (s_c[2] + s_c[3]);
    bsum[blockIdx.x] = make_float2(ts, tc);
  }
}

__global__ __launch_bounds__(256) void final_reduce_kernel(
    const float2* __restrict__ bsum, float* __restrict__ out) {
  int t = threadIdx.x;
  float s = 0.f, c = 0.f;
#pragma unroll
  for (int k = 0; k < NFIN / 256; ++k) {
    float2 v = bsum[t + k * 256];
    s += v.x; c += v.y;
  }
#pragma unroll
  for (int m = 32; m >= 1; m >>= 1) {
    s += __shfl_xor(s, m, 64);
    c += __shfl_xor(c, m, 64);
  }
  __shared__ float s_s[4], s_c[4];
  int wave = t >> 6, lane = t & 63;
  if (lane == 0) { s_s[wave] = s; s_c[wave] = c; }
  __syncthreads();
  if (t == 0) {
    float ts = (s_s[0] + s_s[1]) + (s_s[2] + s_s[3]);
    float tc = (s_c[0] + s_c[1]) + (s_c[2] + s_c[3]);
    out[0] = (tc > 0.f) ? (ts / tc) : 0.f;
  }
}

extern "C" void kernel_launch(void* const* d_in, const int* in_sizes, int n_in,
                              void* d_out, int out_size, void* d_ws, size_t ws_size,
                              hipStream_t stream) {
  const float* feat = (const float*)d_in[0];
  const int* lab = (const int*)d_in[1];
  char* ws = (char*)d_ws;
  unsigned short* Xb = (unsigned short*)(ws + XB_OFF);
  float2* meta = (float2*)(ws + META_OFF);
  float4* part = (float4*)(ws + PART_OFF);
  float2* bsum = (float2*)(ws + BSUM_OFF);
  float* out = (float*)d_out;

  prep_kernel<<<N / 4, 256, 0, stream>>>(feat, lab, Xb, meta);
  mine_kernel<<<NROWBLK * NSLICE, 256, 0, stream>>>(Xb, meta, lab, part);
  finalize_kernel<<<N / 4, 256, 0, stream>>>(feat, part, bsum);
  final_reduce_kernel<<<1, 256, 0, stream>>>(bsum, out);
}

// Round 3
// 56.082 us; speedup vs baseline: 1.5615x; 1.5615x over previous
//
#include <hip/hip_runtime.h>
#include <hip/hip_bf16.h>

#define N 8192
#define DIMS 128
#define NSLICE 16
#define SLICE_COLS (N / NSLICE)       // 512
#define SUBTILES (SLICE_COLS / 16)    // 32
#define ROWS_PER_BLOCK 256
#define STRIPS 4                      // 16-row strips per wave
#define NROWBLK (N / ROWS_PER_BLOCK)  // 32
#define NFIN 2048
#define MARGIN_F 0.2f
#define EPS_F 1e-6f
#define INF_F __builtin_huge_valf()

typedef __bf16 bf16x8 __attribute__((ext_vector_type(8)));
typedef float f32x4 __attribute__((ext_vector_type(4)));

// ws layout (bytes):
//   Xb   : ushort[N*DIMS]      @ 0          (2 MiB)   bf16 features (row-major, 256B/row)
//   meta : float2[N]           @ 2097152    (64 KiB)  {sq, label bits}
//   part : float4[NSLICE*N]    @ 2162688    (2 MiB)   per-slice {bpv, bpi, bnv, bni}
//   bsum : float2[NFIN]        @ 4259840    (16 KiB)
#define XB_OFF   0
#define META_OFF 2097152
#define PART_OFF 2162688
#define BSUM_OFF 4259840

#define GLD_LDS(g, l) \
  __builtin_amdgcn_global_load_lds( \
      (const __attribute__((address_space(1))) void*)(g), \
      (__attribute__((address_space(3))) void*)(l), 16, 0, 0)

// ---------------- prep: fp32 -> bf16, row sq-norm, pack label -------------
__global__ __launch_bounds__(256) void prep_kernel(
    const float* __restrict__ feat, const int* __restrict__ lab,
    unsigned short* __restrict__ Xb, float2* __restrict__ meta) {
  int row = blockIdx.x * 4 + (threadIdx.x >> 6);
  int lane = threadIdx.x & 63;
  float2 x = *reinterpret_cast<const float2*>(feat + (size_t)row * DIMS + lane * 2);
  __hip_bfloat16 hx = __float2bfloat16(x.x);
  __hip_bfloat16 hy = __float2bfloat16(x.y);
  unsigned short ux, uy;
  __builtin_memcpy(&ux, &hx, 2);
  __builtin_memcpy(&uy, &hy, 2);
  unsigned int packed = (unsigned int)ux | ((unsigned int)uy << 16);
  *reinterpret_cast<unsigned int*>(Xb + (size_t)row * DIMS + lane * 2) = packed;
  float s = x.x * x.x + x.y * x.y;
#pragma unroll
  for (int m = 32; m >= 1; m >>= 1) s += __shfl_xor(s, m, 64);
  if (lane == 0) meta[row] = make_float2(s, __int_as_float(lab[row]));
}

// ---------------- mine: LDS-staged bf16 MFMA GEMM + batch-hard mining -----
// grid = NROWBLK*NSLICE = 512 blocks, 256 threads (4 waves).
// Block stages each 16-col B-subtile (4KB) into LDS once (global_load_lds,
// double-buffered); all 4 waves ds_read it. Each wave owns 64 anchor rows.
__global__ __launch_bounds__(256, 2) void mine_kernel(
    const unsigned short* __restrict__ Xb, const float2* __restrict__ meta,
    const int* __restrict__ lab, float4* __restrict__ part) {
  __shared__ char smem[2 * 4096 + 4096];  // B double-buffer + slice meta

  int rb = blockIdx.x / NSLICE;
  int sl = blockIdx.x % NSLICE;
  int tid = threadIdx.x;
  int wave = tid >> 6;
  int lane = tid & 63;
  int lrow = lane & 15;  // B-col / C-col lane index
  int lk = lane >> 4;    // k-subgroup; also C-row group
  int rowbase = rb * ROWS_PER_BLOCK + wave * (STRIPS * 16);
  int j0 = sl * SLICE_COLS;

  // --- stage slice meta (512 * 8B = 4KB) once, linear ---
  {
    const char* g = (const char*)meta + (size_t)j0 * 8 + tid * 16;
    char* l = smem + 8192 + wave * 1024;
    GLD_LDS(g, l);
  }
  // --- stage B subtile 0 (pre-swizzled source, linear LDS dest) ---
  // thread tid -> (col = tid>>4, chunk = tid&15); LDS slot col*256+chunk*16
  // holds global chunk (chunk ^ (col&7)) of row j0+col.  (involution)
  int colt = tid >> 4;
  int chunk = tid & 15;
  const char* gsrc0 = (const char*)Xb + (size_t)(j0 + colt) * 256 +
                      ((chunk ^ (colt & 7)) * 16);
  {
    char* l = smem + wave * 1024;
    GLD_LDS(gsrc0, l);
  }

  // --- A fragments: STRIPS x 4 k-groups, registers for the whole scan ---
  bf16x8 afrag[STRIPS][4];
#pragma unroll
  for (int s = 0; s < STRIPS; ++s) {
    const unsigned short* rp = Xb + (size_t)(rowbase + s * 16 + lrow) * DIMS;
#pragma unroll
    for (int g = 0; g < 4; ++g)
      afrag[s][g] = *reinterpret_cast<const bf16x8*>(rp + g * 32 + lk * 8);
  }
  int4 labi[STRIPS];
#pragma unroll
  for (int s = 0; s < STRIPS; ++s)
    labi[s] = *reinterpret_cast<const int4*>(lab + rowbase + s * 16 + lk * 4);

  float bpv[STRIPS][4], bnv[STRIPS][4];
  int bpi[STRIPS][4], bni[STRIPS][4];
#pragma unroll
  for (int s = 0; s < STRIPS; ++s)
#pragma unroll
    for (int e = 0; e < 4; ++e) {
      bpv[s][e] = -INF_F; bnv[s][e] = INF_F; bpi[s][e] = 0; bni[s][e] = 0;
    }

  // per-lane swizzled B-frag LDS byte offsets (hoisted)
  int boff[4];
#pragma unroll
  for (int g = 0; g < 4; ++g)
    boff[g] = lrow * 256 + (((g * 4 + lk) ^ (lrow & 7)) * 16);

  __syncthreads();  // meta + buf0 staged (drains each wave's vmcnt, then barrier)

  for (int t = 0; t < SUBTILES; ++t) {
    int cur = t & 1;
    if (t + 1 < SUBTILES) {  // uniform branch
      const char* g = gsrc0 + (size_t)(t + 1) * 4096;
      char* l = smem + ((t + 1) & 1) * 4096 + wave * 1024;
      GLD_LDS(g, l);
    }

    float2 mcur = *reinterpret_cast<const float2*>(smem + 8192 + t * 128 + lrow * 8);
    float sqj = mcur.x;
    int labj = __float_as_int(mcur.y);
    int jcur = j0 + t * 16 + lrow;

    const char* bbase = smem + cur * 4096;
    bf16x8 bb[4];
#pragma unroll
    for (int g = 0; g < 4; ++g)
      bb[g] = *reinterpret_cast<const bf16x8*>(bbase + boff[g]);

#pragma unroll
    for (int s = 0; s < STRIPS; ++s) {
      f32x4 acc = {0.f, 0.f, 0.f, 0.f};
#pragma unroll
      for (int g = 0; g < 4; ++g)
        acc = __builtin_amdgcn_mfma_f32_16x16x32_bf16(afrag[s][g], bb[g], acc, 0, 0, 0);
      int labs[4] = {labi[s].x, labi[s].y, labi[s].z, labi[s].w};
#pragma unroll
      for (int e = 0; e < 4; ++e) {
        float key = fmaf(-2.0f, acc[e], sqj);
        bool pos = (labj == labs[e]);
        bool gp = pos && (key > bpv[s][e]);
        bool gn = (!pos) && (key < bnv[s][e]);
        bpv[s][e] = gp ? key : bpv[s][e];
        bpi[s][e] = gp ? jcur : bpi[s][e];
        bnv[s][e] = gn ? key : bnv[s][e];
        bni[s][e] = gn ? jcur : bni[s][e];
      }
    }
    // drains this wave's stage-load (vmcnt) and its ds_reads (lgkm), then
    // barrier: buf[(t+1)&1] fully written, buf[cur] free to overwrite next.
    __syncthreads();
  }

  // merge across the 16 lanes that share each C-row (lane bits 0-3)
#pragma unroll
  for (int s = 0; s < STRIPS; ++s) {
#pragma unroll
    for (int e = 0; e < 4; ++e) {
      float pv = bpv[s][e]; int pi = bpi[s][e];
      float nv = bnv[s][e]; int ni = bni[s][e];
#pragma unroll
      for (int m = 1; m < 16; m <<= 1) {
        float opv = __shfl_xor(pv, m, 64); int opi = __shfl_xor(pi, m, 64);
        float onv = __shfl_xor(nv, m, 64); int oni = __shfl_xor(ni, m, 64);
        bool tp = (opv > pv) || (opv == pv && opi < pi);
        pv = tp ? opv : pv; pi = tp ? opi : pi;
        bool tn = (onv < nv) || (onv == nv && oni < ni);
        nv = tn ? onv : nv; ni = tn ? oni : ni;
      }
      if (lrow == 0) {
        int row = rowbase + s * 16 + lk * 4 + e;
        part[(size_t)sl * N + row] =
            make_float4(pv, __int_as_float(pi), nv, __int_as_float(ni));
      }
    }
  }
}

// ---------------- finalize: wave-per-anchor merge + exact fp32 hinge ------
__global__ __launch_bounds__(256) void finalize_kernel(
    const float* __restrict__ feat, const float4* __restrict__ part,
    float2* __restrict__ bsum) {
  int wave = threadIdx.x >> 6, lane = threadIdx.x & 63;
  int i = blockIdx.x * 4 + wave;

  float pv = -INF_F, nv = INF_F;
  int pi = 0, ni = 0;
  if (lane < NSLICE) {
    float4 p = part[(size_t)lane * N + i];
    pv = p.x; pi = __float_as_int(p.y);
    nv = p.z; ni = __float_as_int(p.w);
  }
#pragma unroll
  for (int m = 1; m < 16; m <<= 1) {
    float opv = __shfl_xor(pv, m, 64); int opi = __shfl_xor(pi, m, 64);
    float onv = __shfl_xor(nv, m, 64); int oni = __shfl_xor(ni, m, 64);
    bool tp = (opv > pv) || (opv == pv && opi < pi);
    pv = tp ? opv : pv; pi = tp ? opi : pi;
    bool tn = (onv < nv) || (onv == nv && oni < ni);
    nv = tn ? onv : nv; ni = tn ? oni : ni;
  }
  pi = __shfl(pi, 0, 64);
  ni = __shfl(ni, 0, 64);
  float nvb = __shfl(nv, 0, 64);
  bool valid = (nvb < INF_F);

  float2 av = *reinterpret_cast<const float2*>(feat + (size_t)i * DIMS + lane * 2);
  float2 pw = *reinterpret_cast<const float2*>(feat + (size_t)pi * DIMS + lane * 2);
  float2 nw = *reinterpret_cast<const float2*>(feat + (size_t)ni * DIMS + lane * 2);
  float d0 = av.x - pw.x + EPS_F, d1 = av.y - pw.y + EPS_F;
  float sp = fmaf(d0, d0, d1 * d1);
  float e0 = av.x - nw.x + EPS_F, e1 = av.y - nw.y + EPS_F;
  float sn = fmaf(e0, e0, e1 * e1);
#pragma unroll
  for (int m = 32; m >= 1; m >>= 1) {
    sp += __shfl_xor(sp, m, 64);
    sn += __shfl_xor(sn, m, 64);
  }

  __shared__ float s_s[4], s_c[4];
  if (lane == 0) {
    float per = sqrtf(sp) - sqrtf(sn) + MARGIN_F;
    per = per > 0.f ? per : 0.f;
    per = valid ? per : 0.f;
    s_s[wave] = per;
    s_c[wave] = valid ? 1.f : 0.f;
  }
  __syncthreads();
  if (threadIdx.x == 0) {
    float ts = (s_s[0] + s_s[1]) + (s_s[2] + s_s[3]);
    float tc = (s_c[0] + s_c[1]) + (s_c[2] + s_c[3]);
    bsum[blockIdx.x] = make_float2(ts, tc);
  }
}

__global__ __launch_bounds__(256) void final_reduce_kernel(
    const float2* __restrict__ bsum, float* __restrict__ out) {
  int t = threadIdx.x;
  float s = 0.f, c = 0.f;
#pragma unroll
  for (int k = 0; k < NFIN / 256; ++k) {
    float2 v = bsum[t + k * 256];
    s += v.x; c += v.y;
  }
#pragma unroll
  for (int m = 32; m >= 1; m >>= 1) {
    s += __shfl_xor(s, m, 64);
    c += __shfl_xor(c, m, 64);
  }
  __shared__ float s_s[4], s_c[4];
  int wave = t >> 6, lane = t & 63;
  if (lane == 0) { s_s[wave] = s; s_c[wave] = c; }
  __syncthreads();
  if (t == 0) {
    float ts = (s_s[0] + s_s[1]) + (s_s[2] + s_s[3]);
    float tc = (s_c[0] + s_c[1]) + (s_c[2] + s_c[3]);
    out[0] = (tc > 0.f) ? (ts / tc) : 0.f;
  }
}

extern "C" void kernel_launch(void* const* d_in, const int* in_sizes, int n_in,
                              void* d_out, int out_size, void* d_ws, size_t ws_size,
                              hipStream_t stream) {
  const float* feat = (const float*)d_in[0];
  const int* lab = (const int*)d_in[1];
  char* ws = (char*)d_ws;
  unsigned short* Xb = (unsigned short*)(ws + XB_OFF);
  float2* meta = (float2*)(ws + META_OFF);
  float4* part = (float4*)(ws + PART_OFF);
  float2* bsum = (float2*)(ws + BSUM_OFF);
  float* out = (float*)d_out;

  prep_kernel<<<N / 4, 256, 0, stream>>>(feat, lab, Xb, meta);
  mine_kernel<<<NROWBLK * NSLICE, 256, 0, stream>>>(Xb, meta, lab, part);
  finalize_kernel<<<N / 4, 256, 0, stream>>>(feat, part, bsum);
  final_reduce_kernel<<<1, 256, 0, stream>>>(bsum, out);
}

// Round 4
// 49.463 us; speedup vs baseline: 1.7704x; 1.1338x over previous
//
#include <hip/hip_runtime.h>
#include <hip/hip_bf16.h>

#define N 8192
#define DIMS 128
#define NSLICE 16
#define SLICE_COLS (N / NSLICE)       // 512
#define SUBTILES (SLICE_COLS / 16)    // 32
#define NSTEPS (SUBTILES / 2)         // 16 (32 cols per barrier step)
#define ROWS_PER_BLOCK 128
#define STRIPS 2                      // 16-row strips per wave
#define NROWBLK (N / ROWS_PER_BLOCK)  // 64
#define NFIN 2048
#define MARGIN_F 0.2f
#define EPS_F 1e-6f
#define INF_F __builtin_huge_valf()

typedef __bf16 bf16x8 __attribute__((ext_vector_type(8)));
typedef float f32x4 __attribute__((ext_vector_type(4)));

// ws layout (bytes):
//   Xb   : ushort[N*DIMS]      @ 0          (2 MiB)   bf16 features (256B/row)
//   meta : float2[N]           @ 2097152    (64 KiB)  {sq, label bits}
//   part : float4[NSLICE*N]    @ 2162688    (2 MiB)   per-slice {bpv,bpi,bnv,bni}
//   bsum : float2[NFIN]        @ 4259840    (16 KiB)
#define XB_OFF   0
#define META_OFF 2097152
#define PART_OFF 2162688
#define BSUM_OFF 4259840

#define GLD_LDS(g, l) \
  __builtin_amdgcn_global_load_lds( \
      (const __attribute__((address_space(1))) void*)(g), \
      (__attribute__((address_space(3))) void*)(l), 16, 0, 0)

// ---------------- prep: fp32 -> bf16, row sq-norm, pack label -------------
__global__ __launch_bounds__(256) void prep_kernel(
    const float* __restrict__ feat, const int* __restrict__ lab,
    unsigned short* __restrict__ Xb, float2* __restrict__ meta) {
  int row = blockIdx.x * 4 + (threadIdx.x >> 6);
  int lane = threadIdx.x & 63;
  float2 x = *reinterpret_cast<const float2*>(feat + (size_t)row * DIMS + lane * 2);
  __hip_bfloat16 hx = __float2bfloat16(x.x);
  __hip_bfloat16 hy = __float2bfloat16(x.y);
  unsigned short ux, uy;
  __builtin_memcpy(&ux, &hx, 2);
  __builtin_memcpy(&uy, &hy, 2);
  unsigned int packed = (unsigned int)ux | ((unsigned int)uy << 16);
  *reinterpret_cast<unsigned int*>(Xb + (size_t)row * DIMS + lane * 2) = packed;
  float s = x.x * x.x + x.y * x.y;
#pragma unroll
  for (int m = 32; m >= 1; m >>= 1) s += __shfl_xor(s, m, 64);
  if (lane == 0) meta[row] = make_float2(s, __int_as_float(lab[row]));
}

// ---------------- mine: LDS-staged bf16 MFMA GEMM + batch-hard mining -----
// grid = NROWBLK*NSLICE = 1024 blocks (4/CU), 256 threads (4 waves).
// Per barrier step the block stages 32 B-cols (8KB) via global_load_lds
// (double-buffered) and computes 2 16-col subtiles. Wave owns 32 anchor rows.
__global__ __launch_bounds__(256, 4) void mine_kernel(
    const unsigned short* __restrict__ Xb, const float2* __restrict__ meta,
    const int* __restrict__ lab, float4* __restrict__ part) {
  __shared__ char smem[2 * 8192 + 4096];  // B double-buffer (8KB each) + meta

  int rb = blockIdx.x / NSLICE;
  int sl = blockIdx.x % NSLICE;
  int tid = threadIdx.x;
  int wave = tid >> 6;
  int lane = tid & 63;
  int lrow = lane & 15;  // B-col / C-col lane index
  int lk = lane >> 4;    // k-subgroup; also C-row group
  int rowbase = rb * ROWS_PER_BLOCK + wave * (STRIPS * 16);
  int j0 = sl * SLICE_COLS;

  // --- stage slice meta (512 * 8B = 4KB) once, linear ---
  {
    const char* g = (const char*)meta + (size_t)j0 * 8 + tid * 16;
    char* l = smem + 16384 + wave * 1024;
    GLD_LDS(g, l);
  }
  // --- B staging geometry: thread tid -> (colt = tid>>4, chunk = tid&15).
  // LDS byte (c*16+colt)*256 + chunk*16 holds global chunk (chunk^(colt&7))
  // of row j0 + c*16 + colt  (involution swizzle; col&7 invariant vs c*16).
  int colt = tid >> 4;
  int chunk = tid & 15;
  const char* gsrc0 = (const char*)Xb + (size_t)(j0 + colt) * 256 +
                      ((chunk ^ (colt & 7)) * 16);
  // stage step 0 into buf 0 (chunks c=0,1 -> 16 cols each)
  {
    GLD_LDS(gsrc0, smem + wave * 1024);
    GLD_LDS(gsrc0 + 16 * 256, smem + 4096 + wave * 1024);
  }

  // --- A fragments: STRIPS x 4 k-groups, registers for the whole scan ---
  bf16x8 afrag[STRIPS][4];
#pragma unroll
  for (int s = 0; s < STRIPS; ++s) {
    const unsigned short* rp = Xb + (size_t)(rowbase + s * 16 + lrow) * DIMS;
#pragma unroll
    for (int g = 0; g < 4; ++g)
      afrag[s][g] = *reinterpret_cast<const bf16x8*>(rp + g * 32 + lk * 8);
  }
  int4 labi[STRIPS];
#pragma unroll
  for (int s = 0; s < STRIPS; ++s)
    labi[s] = *reinterpret_cast<const int4*>(lab + rowbase + s * 16 + lk * 4);

  float bpv[STRIPS][4], bnv[STRIPS][4];
  int bpi[STRIPS][4], bni[STRIPS][4];
#pragma unroll
  for (int s = 0; s < STRIPS; ++s)
#pragma unroll
    for (int e = 0; e < 4; ++e) {
      bpv[s][e] = -INF_F; bnv[s][e] = INF_F; bpi[s][e] = 0; bni[s][e] = 0;
    }

  // per-lane swizzled B-frag LDS byte offsets (hoisted); +h*4096 per half
  int boff[4];
#pragma unroll
  for (int g = 0; g < 4; ++g)
    boff[g] = lrow * 256 + (((g * 4 + lk) ^ (lrow & 7)) * 16);

  __syncthreads();  // meta + step0 staged

  for (int it = 0; it < NSTEPS; ++it) {
    int cur = it & 1;
    if (it + 1 < NSTEPS) {  // uniform branch: prefetch step it+1
      const char* g = gsrc0 + (size_t)(it + 1) * 8192;
      char* l = smem + (cur ^ 1) * 8192 + wave * 1024;
      GLD_LDS(g, l);
      GLD_LDS(g + 16 * 256, l + 4096);
    }

#pragma unroll
    for (int h = 0; h < 2; ++h) {
      int t = it * 2 + h;
      float2 mcur =
          *reinterpret_cast<const float2*>(smem + 16384 + t * 128 + lrow * 8);
      float sqj = mcur.x;
      int labj = __float_as_int(mcur.y);
      int jcur = j0 + t * 16 + lrow;

      const char* bbase = smem + cur * 8192 + h * 4096;
      bf16x8 bb[4];
#pragma unroll
      for (int g = 0; g < 4; ++g)
        bb[g] = *reinterpret_cast<const bf16x8*>(bbase + boff[g]);

#pragma unroll
      for (int s = 0; s < STRIPS; ++s) {
        f32x4 acc = {0.f, 0.f, 0.f, 0.f};
#pragma unroll
        for (int g = 0; g < 4; ++g)
          acc = __builtin_amdgcn_mfma_f32_16x16x32_bf16(afrag[s][g], bb[g], acc,
                                                        0, 0, 0);
        int labs[4] = {labi[s].x, labi[s].y, labi[s].z, labi[s].w};
#pragma unroll
        for (int e = 0; e < 4; ++e) {
          float key = fmaf(-2.0f, acc[e], sqj);
          bool pos = (labj == labs[e]);
          bool gp = pos && (key > bpv[s][e]);
          bool gn = (!pos) && (key < bnv[s][e]);
          bpv[s][e] = gp ? key : bpv[s][e];
          bpi[s][e] = gp ? jcur : bpi[s][e];
          bnv[s][e] = gn ? key : bnv[s][e];
          bni[s][e] = gn ? jcur : bni[s][e];
        }
      }
    }
    // drains this wave's stage-loads (vmcnt) + ds_reads (lgkm), then barrier:
    // buf[cur^1] fully written, buf[cur] free to overwrite next iteration.
    __syncthreads();
  }

  // merge across the 16 lanes that share each C-row (lane bits 0-3)
#pragma unroll
  for (int s = 0; s < STRIPS; ++s) {
#pragma unroll
    for (int e = 0; e < 4; ++e) {
      float pv = bpv[s][e]; int pi = bpi[s][e];
      float nv = bnv[s][e]; int ni = bni[s][e];
#pragma unroll
      for (int m = 1; m < 16; m <<= 1) {
        float opv = __shfl_xor(pv, m, 64); int opi = __shfl_xor(pi, m, 64);
        float onv = __shfl_xor(nv, m, 64); int oni = __shfl_xor(ni, m, 64);
        bool tp = (opv > pv) || (opv == pv && opi < pi);
        pv = tp ? opv : pv; pi = tp ? opi : pi;
        bool tn = (onv < nv) || (onv == nv && oni < ni);
        nv = tn ? onv : nv; ni = tn ? oni : ni;
      }
      if (lrow == 0) {
        int row = rowbase + s * 16 + lk * 4 + e;
        part[(size_t)sl * N + row] =
            make_float4(pv, __int_as_float(pi), nv, __int_as_float(ni));
      }
    }
  }
}

// ---------------- finalize: wave-per-anchor merge + exact fp32 hinge ------
__global__ __launch_bounds__(256) void finalize_kernel(
    const float* __restrict__ feat, const float4* __restrict__ part,
    float2* __restrict__ bsum) {
  int wave = threadIdx.x >> 6, lane = threadIdx.x & 63;
  int i = blockIdx.x * 4 + wave;

  float pv = -INF_F, nv = INF_F;
  int pi = 0, ni = 0;
  if (lane < NSLICE) {
    float4 p = part[(size_t)lane * N + i];
    pv = p.x; pi = __float_as_int(p.y);
    nv = p.z; ni = __float_as_int(p.w);
  }
#pragma unroll
  for (int m = 1; m < 16; m <<= 1) {
    float opv = __shfl_xor(pv, m, 64); int opi = __shfl_xor(pi, m, 64);
    float onv = __shfl_xor(nv, m, 64); int oni = __shfl_xor(ni, m, 64);
    bool tp = (opv > pv) || (opv == pv && opi < pi);
    pv = tp ? opv : pv; pi = tp ? opi : pi;
    bool tn = (onv < nv) || (onv == nv && oni < ni);
    nv = tn ? onv : nv; ni = tn ? oni : ni;
  }
  pi = __shfl(pi, 0, 64);
  ni = __shfl(ni, 0, 64);
  float nvb = __shfl(nv, 0, 64);
  bool valid = (nvb < INF_F);

  float2 av = *reinterpret_cast<const float2*>(feat + (size_t)i * DIMS + lane * 2);
  float2 pw = *reinterpret_cast<const float2*>(feat + (size_t)pi * DIMS + lane * 2);
  float2 nw = *reinterpret_cast<const float2*>(feat + (size_t)ni * DIMS + lane * 2);
  float d0 = av.x - pw.x + EPS_F, d1 = av.y - pw.y + EPS_F;
  float sp = fmaf(d0, d0, d1 * d1);
  float e0 = av.x - nw.x + EPS_F, e1 = av.y - nw.y + EPS_F;
  float sn = fmaf(e0, e0, e1 * e1);
#pragma unroll
  for (int m = 32; m >= 1; m >>= 1) {
    sp += __shfl_xor(sp, m, 64);
    sn += __shfl_xor(sn, m, 64);
  }

  __shared__ float s_s[4], s_c[4];
  if (lane == 0) {
    float per = sqrtf(sp) - sqrtf(sn) + MARGIN_F;
    per = per > 0.f ? per : 0.f;
    per = valid ? per : 0.f;
    s_s[wave] = per;
    s_c[wave] = valid ? 1.f : 0.f;
  }
  __syncthreads();
  if (threadIdx.x == 0) {
    float ts = (s_s[0] + s_s[1]) + (s_s[2] + s_s[3]);
    float tc = (s_c[0] + s_c[1]) + (s_c[2] + s_c[3]);
    bsum[blockIdx.x] = make_float2(ts, tc);
  }
}

__global__ __launch_bounds__(256) void final_reduce_kernel(
    const float2* __restrict__ bsum, float* __restrict__ out) {
  int t = threadIdx.x;
  float s = 0.f, c = 0.f;
#pragma unroll
  for (int k = 0; k < NFIN / 256; ++k) {
    float2 v = bsum[t + k * 256];
    s += v.x; c += v.y;
  }
#pragma unroll
  for (int m = 32; m >= 1; m >>= 1) {
    s += __shfl_xor(s, m, 64);
    c += __shfl_xor(c, m, 64);
  }
  __shared__ float s_s[4], s_c[4];
  int wave = t >> 6, lane = t & 63;
  if (lane == 0) { s_s[wave] = s; s_c[wave] = c; }
  __syncthreads();
  if (t == 0) {
    float ts = (s_s[0] + s_s[1]) + (s_s[2] + s_s[3]);
    float tc = (s_c[0] + s_c[1]) + (s_c[2] + s_c[3]);
    out[0] = (tc > 0.f) ? (ts / tc) : 0.f;
  }
}

extern "C" void kernel_launch(void* const* d_in, const int* in_sizes, int n_in,
                              void* d_out, int out_size, void* d_ws, size_t ws_size,
                              hipStream_t stream) {
  const float* feat = (const float*)d_in[0];
  const int* lab = (const int*)d_in[1];
  char* ws = (char*)d_ws;
  unsigned short* Xb = (unsigned short*)(ws + XB_OFF);
  float2* meta = (float2*)(ws + META_OFF);
  float4* part = (float4*)(ws + PART_OFF);
  float2* bsum = (float2*)(ws + BSUM_OFF);
  float* out = (float*)d_out;

  prep_kernel<<<N / 4, 256, 0, stream>>>(feat, lab, Xb, meta);
  mine_kernel<<<NROWBLK * NSLICE, 256, 0, stream>>>(Xb, meta, lab, part);
  finalize_kernel<<<N / 4, 256, 0, stream>>>(feat, part, bsum);
  final_reduce_kernel<<<1, 256, 0, stream>>>(bsum, out);
}

// Round 5
// 47.715 us; speedup vs baseline: 1.8353x; 1.0366x over previous
//
#include <hip/hip_runtime.h>
#include <hip/hip_bf16.h>

#define N 8192
#define DIMS 128
#define NSLICE 32
#define SLICE_COLS (N / NSLICE)       // 256
#define SUBTILES (SLICE_COLS / 16)    // 16
#define NSTEPS (SUBTILES / 2)         // 8 (32 cols per barrier step)
#define ROWS_PER_BLOCK 256
#define STRIPS 4                      // 16-row strips per wave (64 rows/wave)
#define NROWBLK (N / ROWS_PER_BLOCK)  // 32
#define NFIN 2048
#define MARGIN_F 0.2f
#define EPS_F 1e-6f
#define BIAS_F 512.0f                 // makes key' = 512 + sqj - 2dot > 0 (Cauchy-Schwarz)
#define INF_F __builtin_huge_valf()

typedef __bf16 bf16x8 __attribute__((ext_vector_type(8)));
typedef float f32x4 __attribute__((ext_vector_type(4)));

// ws layout (bytes), ws_size = 256 MiB (observed via harness poison fill):
//   Xb   : ushort[N*DIMS]      @ 0          (2 MiB)   bf16 features (256B/row)
//   meta : float2[N]           @ 2097152    (64 KiB)  {sq+512, label bits}
//   part : uint2[NSLICE*N]     @ 2162688    (2 MiB)   packed {max_pos_u, min_neg_u}
//   bsum : float2[NFIN]        @ 4259840    (16 KiB)
#define XB_OFF   0
#define META_OFF 2097152
#define PART_OFF 2162688
#define BSUM_OFF 4259840

#define GLD_LDS(g, l) \
  __builtin_amdgcn_global_load_lds( \
      (const __attribute__((address_space(1))) void*)(g), \
      (__attribute__((address_space(3))) void*)(l), 16, 0, 0)

// ---------------- prep: fp32 -> bf16, row sq-norm(+bias), pack label ------
__global__ __launch_bounds__(256) void prep_kernel(
    const float* __restrict__ feat, const int* __restrict__ lab,
    unsigned short* __restrict__ Xb, float2* __restrict__ meta) {
  int row = blockIdx.x * 4 + (threadIdx.x >> 6);
  int lane = threadIdx.x & 63;
  float2 x = *reinterpret_cast<const float2*>(feat + (size_t)row * DIMS + lane * 2);
  __hip_bfloat16 hx = __float2bfloat16(x.x);
  __hip_bfloat16 hy = __float2bfloat16(x.y);
  unsigned short ux, uy;
  __builtin_memcpy(&ux, &hx, 2);
  __builtin_memcpy(&uy, &hy, 2);
  unsigned int packed = (unsigned int)ux | ((unsigned int)uy << 16);
  *reinterpret_cast<unsigned int*>(Xb + (size_t)row * DIMS + lane * 2) = packed;
  float s = x.x * x.x + x.y * x.y;
#pragma unroll
  for (int m = 32; m >= 1; m >>= 1) s += __shfl_xor(s, m, 64);
  if (lane == 0) meta[row] = make_float2(s + BIAS_F, __int_as_float(lab[row]));
}

// ---------------- mine: LDS-staged bf16 MFMA GEMM + packed mining ---------
// grid = NROWBLK*NSLICE = 1024 blocks (3/CU at ~150 VGPR), 256 thr (4 waves).
// Wave owns 64 anchor rows (4 strips); block stages 32 B-cols (8KB) per
// barrier step via global_load_lds (double-buffered), computes 2 subtiles.
// Mining key packed: u = (bits(512+sqj-2dot) & ~0x1FFF) | j  (u > 0 always;
// uint order == float order since key' > 0; 13 low bits hold j exactly).
__global__ __launch_bounds__(256, 3) void mine_kernel(
    const unsigned short* __restrict__ Xb, const float2* __restrict__ meta,
    const int* __restrict__ lab, uint2* __restrict__ part) {
  __shared__ char smem[2 * 8192 + 2048];  // B double-buffer (8KB each) + meta

  int rb = blockIdx.x / NSLICE;
  int sl = blockIdx.x % NSLICE;
  int tid = threadIdx.x;
  int wave = tid >> 6;
  int lane = tid & 63;
  int lrow = lane & 15;  // B-col / C-col lane index
  int lk = lane >> 4;    // k-subgroup; also C-row group
  int rowbase = rb * ROWS_PER_BLOCK + wave * (STRIPS * 16);
  int j0 = sl * SLICE_COLS;

  // --- stage slice meta (256 * 8B = 2KB) once: waves 0,1 (uniform branch) ---
  if (wave < 2) {
    const char* g = (const char*)meta + (size_t)j0 * 8 + tid * 16;
    char* l = smem + 16384 + wave * 1024;
    GLD_LDS(g, l);
  }
  // --- B staging: thread tid -> (colt = tid>>4, chunk = tid&15).
  // LDS byte (c*16+colt)*256 + chunk*16 holds global chunk (chunk^(colt&7))
  // of row j0 + c*16 + colt  (involution swizzle, col&7 invariant vs c*16).
  int colt = tid >> 4;
  int chunk = tid & 15;
  const char* gsrc0 = (const char*)Xb + (size_t)(j0 + colt) * 256 +
                      ((chunk ^ (colt & 7)) * 16);
  {  // stage step 0 into buf 0
    GLD_LDS(gsrc0, smem + wave * 1024);
    GLD_LDS(gsrc0 + 4096, smem + 4096 + wave * 1024);
  }

  // --- A fragments: STRIPS x 4 k-groups, registers for the whole scan ---
  bf16x8 afrag[STRIPS][4];
#pragma unroll
  for (int s = 0; s < STRIPS; ++s) {
    const unsigned short* rp = Xb + (size_t)(rowbase + s * 16 + lrow) * DIMS;
#pragma unroll
    for (int g = 0; g < 4; ++g)
      afrag[s][g] = *reinterpret_cast<const bf16x8*>(rp + g * 32 + lk * 8);
  }
  int4 labi[STRIPS];
#pragma unroll
  for (int s = 0; s < STRIPS; ++s)
    labi[s] = *reinterpret_cast<const int4*>(lab + rowbase + s * 16 + lk * 4);

  unsigned int bpu[STRIPS][4], bnu[STRIPS][4];
#pragma unroll
  for (int s = 0; s < STRIPS; ++s)
#pragma unroll
    for (int e = 0; e < 4; ++e) { bpu[s][e] = 0u; bnu[s][e] = 0xFFFFFFFFu; }

  // per-lane swizzled B-frag LDS byte offsets (hoisted); +h*4096 per subtile
  int boff[4];
#pragma unroll
  for (int g = 0; g < 4; ++g)
    boff[g] = lrow * 256 + (((g * 4 + lk) ^ (lrow & 7)) * 16);

  __syncthreads();  // meta + step0 staged

  for (int it = 0; it < NSTEPS; ++it) {
    int cur = it & 1;
    if (it + 1 < NSTEPS) {  // uniform branch: prefetch step it+1
      const char* g = gsrc0 + (size_t)(it + 1) * 8192;
      char* l = smem + (cur ^ 1) * 8192 + wave * 1024;
      GLD_LDS(g, l);
      GLD_LDS(g + 4096, l + 4096);
    }

#pragma unroll
    for (int h = 0; h < 2; ++h) {
      int t = it * 2 + h;
      float2 mcur =
          *reinterpret_cast<const float2*>(smem + 16384 + t * 128 + lrow * 8);
      float sqjB = mcur.x;  // sq_j + 512
      int labj = __float_as_int(mcur.y);
      unsigned int ju = (unsigned int)(j0 + t * 16 + lrow);

      const char* bbase = smem + cur * 8192 + h * 4096;
      bf16x8 bb[4];
#pragma unroll
      for (int g = 0; g < 4; ++g)
        bb[g] = *reinterpret_cast<const bf16x8*>(bbase + boff[g]);

#pragma unroll
      for (int s = 0; s < STRIPS; ++s) {
        f32x4 acc = {0.f, 0.f, 0.f, 0.f};
#pragma unroll
        for (int g = 0; g < 4; ++g)
          acc = __builtin_amdgcn_mfma_f32_16x16x32_bf16(afrag[s][g], bb[g], acc,
                                                        0, 0, 0);
        int labs[4] = {labi[s].x, labi[s].y, labi[s].z, labi[s].w};
#pragma unroll
        for (int e = 0; e < 4; ++e) {
          float key = fmaf(-2.0f, acc[e], sqjB);  // 512 + d^2 - sq_i > 0
          unsigned int u = (__float_as_uint(key) & 0xFFFFE000u) | ju;
          bool pos = (labj == labs[e]);
          unsigned int up = pos ? u : 0u;
          unsigned int un = pos ? 0xFFFFFFFFu : u;
          bpu[s][e] = max(bpu[s][e], up);
          bnu[s][e] = min(bnu[s][e], un);
        }
      }
    }
    // drains stage-loads (vmcnt) + ds_reads (lgkm), then barrier.
    __syncthreads();
  }

  // merge across the 16 lanes that share each C-row (lane bits 0-3)
#pragma unroll
  for (int s = 0; s < STRIPS; ++s) {
#pragma unroll
    for (int e = 0; e < 4; ++e) {
      unsigned int pu = bpu[s][e], nu = bnu[s][e];
#pragma unroll
      for (int m = 1; m < 16; m <<= 1) {
        pu = max(pu, (unsigned int)__shfl_xor((int)pu, m, 64));
        nu = min(nu, (unsigned int)__shfl_xor((int)nu, m, 64));
      }
      if (lrow == 0) {
        int row = rowbase + s * 16 + lk * 4 + e;
        part[(size_t)sl * N + row] = make_uint2(pu, nu);
      }
    }
  }
}

// ---------------- finalize: wave-per-anchor merge + exact fp32 hinge ------
__global__ __launch_bounds__(256) void finalize_kernel(
    const float* __restrict__ feat, const uint2* __restrict__ part,
    float2* __restrict__ bsum) {
  int wave = threadIdx.x >> 6, lane = threadIdx.x & 63;
  int i = blockIdx.x * 4 + wave;

  unsigned int pu = 0u, nu = 0xFFFFFFFFu;
  if (lane < NSLICE) {
    uint2 p = part[(size_t)lane * N + i];
    pu = p.x; nu = p.y;
  }
#pragma unroll
  for (int m = 1; m < 32; m <<= 1) {
    pu = max(pu, (unsigned int)__shfl_xor((int)pu, m, 64));
    nu = min(nu, (unsigned int)__shfl_xor((int)nu, m, 64));
  }
  pu = (unsigned int)__shfl((int)pu, 0, 64);
  nu = (unsigned int)__shfl((int)nu, 0, 64);
  bool valid = (nu != 0xFFFFFFFFu);
  int pi = (int)(pu & 8191u);
  int ni = (int)(nu & 8191u);

  float2 av = *reinterpret_cast<const float2*>(feat + (size_t)i * DIMS + lane * 2);
  float2 pw = *reinterpret_cast<const float2*>(feat + (size_t)pi * DIMS + lane * 2);
  float2 nw = *reinterpret_cast<const float2*>(feat + (size_t)ni * DIMS + lane * 2);
  float d0 = av.x - pw.x + EPS_F, d1 = av.y - pw.y + EPS_F;
  float sp = fmaf(d0, d0, d1 * d1);
  float e0 = av.x - nw.x + EPS_F, e1 = av.y - nw.y + EPS_F;
  float sn = fmaf(e0, e0, e1 * e1);
#pragma unroll
  for (int m = 32; m >= 1; m >>= 1) {
    sp += __shfl_xor(sp, m, 64);
    sn += __shfl_xor(sn, m, 64);
  }

  __shared__ float s_s[4], s_c[4];
  if (lane == 0) {
    float per = sqrtf(sp) - sqrtf(sn) + MARGIN_F;
    per = per > 0.f ? per : 0.f;
    per = valid ? per : 0.f;
    s_s[wave] = per;
    s_c[wave] = valid ? 1.f : 0.f;
  }
  __syncthreads();
  if (threadIdx.x == 0) {
    float ts = (s_s[0] + s_s[1]) + (s_s[2] + s_s[3]);
    float tc = (s_c[0] + s_c[1]) + (s_c[2] + s_c[3]);
    bsum[blockIdx.x] = make_float2(ts, tc);
  }
}

__global__ __launch_bounds__(256) void final_reduce_kernel(
    const float2* __restrict__ bsum, float* __restrict__ out) {
  int t = threadIdx.x;
  float s = 0.f, c = 0.f;
#pragma unroll
  for (int k = 0; k < NFIN / 256; ++k) {
    float2 v = bsum[t + k * 256];
    s += v.x; c += v.y;
  }
#pragma unroll
  for (int m = 32; m >= 1; m >>= 1) {
    s += __shfl_xor(s, m, 64);
    c += __shfl_xor(c, m, 64);
  }
  __shared__ float s_s[4], s_c[4];
  int wave = t >> 6, lane = t & 63;
  if (lane == 0) { s_s[wave] = s; s_c[wave] = c; }
  __syncthreads();
  if (t == 0) {
    float ts = (s_s[0] + s_s[1]) + (s_s[2] + s_s[3]);
    float tc = (s_c[0] + s_c[1]) + (s_c[2] + s_c[3]);
    out[0] = (tc > 0.f) ? (ts / tc) : 0.f;
  }
}

extern "C" void kernel_launch(void* const* d_in, const int* in_sizes, int n_in,
                              void* d_out, int out_size, void* d_ws, size_t ws_size,
                              hipStream_t stream) {
  const float* feat = (const float*)d_in[0];
  const int* lab = (const int*)d_in[1];
  char* ws = (char*)d_ws;
  unsigned short* Xb = (unsigned short*)(ws + XB_OFF);
  float2* meta = (float2*)(ws + META_OFF);
  uint2* part = (uint2*)(ws + PART_OFF);
  float2* bsum = (float2*)(ws + BSUM_OFF);
  float* out = (float*)d_out;

  prep_kernel<<<N / 4, 256, 0, stream>>>(feat, lab, Xb, meta);
  mine_kernel<<<NROWBLK * NSLICE, 256, 0, stream>>>(Xb, meta, lab, part);
  finalize_kernel<<<N / 4, 256, 0, stream>>>(feat, part, bsum);
  final_reduce_kernel<<<1, 256, 0, stream>>>(bsum, out);
}